// Round 13
// baseline (1827.857 us; speedup 1.0000x reference)
//
#include <hip/hip_runtime.h>

typedef __attribute__((ext_vector_type(8))) __bf16 bf16x8;
typedef __attribute__((ext_vector_type(4))) float f32x4;

#define MFMA16(a, b, c) __builtin_amdgcn_mfma_f32_16x16x32_bf16(a, b, c, 0, 0, 0)

#define T_SEQ 512
#define F_IN 32
#define H1 128
#define E2 64

__device__ __forceinline__ float bf2f(ushort u) {
    union { uint i; float f; } v; v.i = ((uint)u) << 16; return v.f;
}
__device__ __forceinline__ ushort f2bf(float f) {
    union { float f; uint i; } v; v.f = f;
    uint r = v.i + 0x7fffu + ((v.i >> 16) & 1u);
    return (ushort)(r >> 16);
}
__device__ __forceinline__ float fast_sigmoid(float x) {
    float e = __expf(-x);
    return __builtin_amdgcn_rcpf(1.0f + e);
}
__device__ __forceinline__ float fast_tanh(float x) {
    float e = __expf(-2.0f * x);
    return 2.0f * __builtin_amdgcn_rcpf(1.0f + e) - 1.0f;
}
__device__ __forceinline__ bf16x8 load_w8(const float* p) {
    bf16x8 r;
#pragma unroll
    for (int j = 0; j < 8; ++j) r[j] = (__bf16)p[j];
    return r;
}
// LDS-only barrier: orders ds ops across waves WITHOUT draining vmcnt.
__device__ __forceinline__ void bar_lds() {
    __asm__ __volatile__("s_waitcnt lgkmcnt(0)\n\ts_barrier" ::: "memory");
}

// Fused 2-layer LSTM, two-phase, ONE batch row per block, 512 blocks x 256
// threads -> 2 blocks/CU co-resident (176 VGPR x 2 = 352 <= 512/SIMD).
// Round-12 structure unchanged otherwise. Rationale: r9/r10/r12 all plateau
// at ~4.4k cyc/step with 1 MFMA wave/SIMD; measured 16.6 cyc/MFMA (vs 4.85
// ubench with many waves) => single-wave issue gaps + exposed serial chain.
// Two independent rows interleaved per SIMD fill each other's gaps.
__global__ __launch_bounds__(256, 1) void lstm_fused(
    const float* __restrict__ x,      // [512][512][32]
    const float* __restrict__ Wih1,   // [512][32]
    const float* __restrict__ Whh1,   // [512][128]
    const float* __restrict__ bih1,   // [512]
    const float* __restrict__ bhh1,   // [512]
    const float* __restrict__ Wih2,   // [256][128]
    const float* __restrict__ Whh2,   // [256][64]
    const float* __restrict__ bih2,   // [256]
    const float* __restrict__ bhh2,   // [256]
    ushort* __restrict__ h1ws,        // [512][512][128] bf16 hi (64 MiB d_ws)
    float* __restrict__ out)          // [512][64] fp32
{
    __shared__ ushort xs [16][72];    // x(t): cols 0..31 hi, 32..63 lo (row 0 live)
    __shared__ ushort h1s[16][264];   // h1: cols 0..127 hi, 128..255 lo
    __shared__ ushort h2s[16][136];   // h2: cols 0..63 hi, 64..127 lo
    __shared__ float  g1r[516];       // raw L1 gates (single row)
    __shared__ float  g2r[260];       // raw L2 gates

    const int tid  = threadIdx.x;
    const int wave = tid >> 6;        // = gate type (i,f,g,o) in both phases
    const int lane = tid & 63;
    const int l15  = lane & 15;
    const int quad = lane >> 4;
    const int r0   = blockIdx.x;      // ONE batch row per block

    bf16x8 wf[40];
    float  bias[8];

    // ---- phase-1 weights: wave w owns L1 gate cols n=(w*8+j)*16+l15 ----
#pragma unroll
    for (int j = 0; j < 8; ++j) {
        const int n = (wave * 8 + j) * 16 + l15;
#pragma unroll
        for (int kt = 0; kt < 4; ++kt)
            wf[j * 4 + kt] = load_w8(Whh1 + n * H1 + kt * 32 + quad * 8);
        wf[32 + j] = load_w8(Wih1 + n * F_IN + quad * 8);
        bias[j] = bih1[n] + bhh1[n];
    }

    // zero LDS state (A-operand reads touch all 16 rows; rows >= 1 stay 0)
    for (int i = tid; i < 16 * 264; i += 256) ((ushort*)h1s)[i] = 0;
    for (int i = tid; i < 16 * 136; i += 256) ((ushort*)h2s)[i] = 0;
    for (int i = tid; i < 16 * 72;  i += 256) ((ushort*)xs)[i]  = 0;
    __syncthreads();

    // ---------------- PHASE 1: layer 1, t = 0..511 ----------------
    {
        float c1 = 0.0f;                               // tid<128: unit tid
        const float* xptr = x + ((size_t)r0 * T_SEQ) * F_IN + tid;  // tid<32
        float xreg = (tid < 32) ? xptr[0] : 0.0f;

        f32x4 acc[8];

#pragma unroll 1
        for (int t = 0; t < T_SEQ; ++t) {
            if (tid < 32) {
                const ushort h = f2bf(xreg);
                xs[0][tid]      = h;
                xs[0][32 + tid] = f2bf(xreg - bf2f(h));
                if (t + 1 < T_SEQ) xreg = xptr[(t + 1) * F_IN];
            }
            bar_lds();   // B1: xs(t), h1s(t-1) visible

#pragma unroll
            for (int j = 0; j < 8; ++j)
                acc[j] = (f32x4){bias[j], bias[j], bias[j], bias[j]};
#pragma unroll
            for (int xt = 0; xt < 2; ++xt) {   // x hi, lo
                const bf16x8 ax = *(const bf16x8*)&xs[l15][xt * 32 + quad * 8];
#pragma unroll
                for (int j = 0; j < 8; ++j)
                    acc[j] = MFMA16(ax, wf[32 + j], acc[j]);
            }
#pragma unroll
            for (int kt = 0; kt < 8; ++kt) {   // h1 hi (0-3), lo (4-7)
                const bf16x8 ah = *(const bf16x8*)&h1s[l15][kt * 32 + quad * 8];
#pragma unroll
                for (int j = 0; j < 8; ++j)
                    acc[j] = MFMA16(ah, wf[j * 4 + (kt & 3)], acc[j]);
            }
            if (quad == 0) {   // row 0 of C = acc[j][0]
#pragma unroll
                for (int j = 0; j < 8; ++j)
                    g1r[(wave * 8 + j) * 16 + l15] = acc[j][0];
            }
            bar_lds();   // B2: g1r ready; h1s/xs reads done

            if (tid < 128) {   // 1 update/thread, unit = tid
                const float iv = fast_sigmoid(g1r[tid]);
                const float fv = fast_sigmoid(g1r[128 + tid]);
                const float gv = fast_tanh   (g1r[256 + tid]);
                const float ov = fast_sigmoid(g1r[384 + tid]);
                const float cn = fv * c1 + iv * gv;
                c1 = cn;
                const float h = ov * fast_tanh(cn);
                const ushort hi = f2bf(h);
                h1s[0][tid]       = hi;
                h1s[0][128 + tid] = f2bf(h - bf2f(hi));
                h1ws[((size_t)r0 * T_SEQ + t) * H1 + tid] = hi;
            }
            // next-iter B1 covers h1s visibility
        }
    }

    __syncthreads();   // drain phase-1 (incl. global h1 writes via memory fence)

    // ---- phase-2 weights: wave w owns L2 gate cols n = w*64 + j*16 + l15 ----
#pragma unroll
    for (int j = 0; j < 4; ++j) {
        const int n = wave * 64 + j * 16 + l15;
#pragma unroll
        for (int kt = 0; kt < 4; ++kt)
            wf[j * 4 + kt] = load_w8(Wih2 + n * H1 + kt * 32 + quad * 8);
#pragma unroll
        for (int kt = 0; kt < 2; ++kt)
            wf[16 + j * 2 + kt] = load_w8(Whh2 + n * E2 + kt * 32 + quad * 8);
        bias[j] = bih2[n] + bhh2[n];
    }

    // ---------------- PHASE 2: layer 2, t = 0..511 ----------------
    {
        float c2 = 0.0f;                               // tid<64: unit tid
        const uint* uptr = (const uint*)h1ws + ((size_t)r0 * T_SEQ) * 64 + tid;
        uint ureg = (tid < 64) ? uptr[0] : 0u;

        f32x4 acc[4];

#pragma unroll 1
        for (int t = 0; t < T_SEQ; ++t) {
            if (tid < 64) {
                *(uint*)&h1s[0][2 * tid] = ureg;   // 2 adjacent bf16 hi
                if (t + 1 < T_SEQ) ureg = uptr[(size_t)(t + 1) * 64];
            }
            bar_lds();   // B1: h1s(t), h2s(t-1) visible

#pragma unroll
            for (int j = 0; j < 4; ++j)
                acc[j] = (f32x4){bias[j], bias[j], bias[j], bias[j]};
#pragma unroll
            for (int kt = 0; kt < 4; ++kt) {   // h1 hi only (cols 0..127)
                const bf16x8 a = *(const bf16x8*)&h1s[l15][kt * 32 + quad * 8];
#pragma unroll
                for (int j = 0; j < 4; ++j)
                    acc[j] = MFMA16(a, wf[j * 4 + kt], acc[j]);
            }
#pragma unroll
            for (int kt = 0; kt < 4; ++kt) {   // h2 hi (0-1), lo (2-3)
                const bf16x8 a = *(const bf16x8*)&h2s[l15][kt * 32 + quad * 8];
#pragma unroll
                for (int j = 0; j < 4; ++j)
                    acc[j] = MFMA16(a, wf[16 + j * 2 + (kt & 1)], acc[j]);
            }
            if (quad == 0) {
#pragma unroll
                for (int j = 0; j < 4; ++j)
                    g2r[wave * 64 + j * 16 + l15] = acc[j][0];
            }
            bar_lds();   // B2: g2r ready; h1s/h2s reads done

            if (tid < 64) {
                const float iv = fast_sigmoid(g2r[tid]);
                const float fv = fast_sigmoid(g2r[64 + tid]);
                const float gv = fast_tanh   (g2r[128 + tid]);
                const float ov = fast_sigmoid(g2r[192 + tid]);
                const float cn = fv * c2 + iv * gv;
                c2 = cn;
                const float h = ov * fast_tanh(cn);
                const ushort hi = f2bf(h);
                h2s[0][tid]      = hi;
                h2s[0][64 + tid] = f2bf(h - bf2f(hi));
                if (t == T_SEQ - 1)
                    out[(size_t)r0 * E2 + tid] = h;
            }
        }
    }
}

extern "C" void kernel_launch(void* const* d_in, const int* in_sizes, int n_in,
                              void* d_out, int out_size, void* d_ws, size_t ws_size,
                              hipStream_t stream) {
    lstm_fused<<<512, 256, 0, stream>>>(
        (const float*)d_in[0], (const float*)d_in[1], (const float*)d_in[2],
        (const float*)d_in[3], (const float*)d_in[4], (const float*)d_in[5],
        (const float*)d_in[6], (const float*)d_in[7], (const float*)d_in[8],
        (ushort*)d_ws, (float*)d_out);
}

// Round 14
// 1046.414 us; speedup vs baseline: 1.7468x; 1.7468x over previous
//
#include <hip/hip_runtime.h>

typedef __attribute__((ext_vector_type(8))) __bf16 bf16x8;
typedef __attribute__((ext_vector_type(4))) float f32x4;

#define MFMA16(a, b, c) __builtin_amdgcn_mfma_f32_16x16x32_bf16(a, b, c, 0, 0, 0)

#define T_SEQ 512
#define F_IN 32
#define H1 128
#define E2 64
#define ROWS 2

__device__ __forceinline__ float bf2f(ushort u) {
    union { uint i; float f; } v; v.i = ((uint)u) << 16; return v.f;
}
__device__ __forceinline__ ushort f2bf(float f) {
    union { float f; uint i; } v; v.f = f;
    uint r = v.i + 0x7fffu + ((v.i >> 16) & 1u);
    return (ushort)(r >> 16);
}
__device__ __forceinline__ float fast_sigmoid(float x) {
    float e = __expf(-x);
    return __builtin_amdgcn_rcpf(1.0f + e);
}
__device__ __forceinline__ float fast_tanh(float x) {
    float e = __expf(-2.0f * x);
    return 2.0f * __builtin_amdgcn_rcpf(1.0f + e) - 1.0f;
}
__device__ __forceinline__ bf16x8 load_w8(const float* p) {
    bf16x8 r;
#pragma unroll
    for (int j = 0; j < 8; ++j) r[j] = (__bf16)p[j];
    return r;
}
// LDS-only barrier: orders ds ops across waves WITHOUT draining vmcnt.
__device__ __forceinline__ void bar_lds() {
    __asm__ __volatile__("s_waitcnt lgkmcnt(0)\n\ts_barrier" ::: "memory");
}

// Fused 2-layer LSTM, two-phase, 256 blocks x 256 threads, 2 rows/block.
// NEW vs r12: wave owns ALL FOUR gates of its unit-slice -> i/f/g/o of a
// unit live in one lane's accumulators (C-layout rows 0..1 = quad-0 lanes).
// Epilogue fully in registers: gate-LDS round-trip deleted, ONE barrier/step
// (xs/h1/h2 double-buffered by parity). r8-r13 post-mortems: per-layer-step
// chain was ~2240 cyc, ~90% fixed latency (2 barriers + 2 LDS round-trips),
// identical for 80-MFMA L1 and 32-MFMA L2. This cuts the fixed part.
__global__ __launch_bounds__(256, 1) void lstm_fused(
    const float* __restrict__ x,      // [512][512][32]
    const float* __restrict__ Wih1,   // [512][32]
    const float* __restrict__ Whh1,   // [512][128]
    const float* __restrict__ bih1,   // [512]
    const float* __restrict__ bhh1,   // [512]
    const float* __restrict__ Wih2,   // [256][128]
    const float* __restrict__ Whh2,   // [256][64]
    const float* __restrict__ bih2,   // [256]
    const float* __restrict__ bhh2,   // [256]
    ushort* __restrict__ h1ws,        // [512][512][128] bf16 hi (64 MiB d_ws)
    float* __restrict__ out)          // [512][64] fp32
{
    __shared__ ushort xs [2][16][72];    // x: cols 0..31 hi, 32..63 lo
    __shared__ ushort h1b[2][16][264];   // h1: 0..127 hi, 128..255 lo (p2: hi staging)
    __shared__ ushort h2b[2][16][136];   // h2: 0..63 hi, 64..127 lo

    const int tid  = threadIdx.x;
    const int wave = tid >> 6;
    const int lane = tid & 63;
    const int l15  = lane & 15;
    const int quad = lane >> 4;
    const int r0   = blockIdx.x * ROWS;

    bf16x8 wf[40];
    float  bias[8];

    // ---- phase-1 weights: wave owns units w*32 + j*16 + l15 (j<2), all gates.
    //  wf[g*8 + j*4 + kt] = Whh1 frag; wf[32 + g*2 + j] = Wih1 frag.
#pragma unroll
    for (int g = 0; g < 4; ++g)
#pragma unroll
        for (int j = 0; j < 2; ++j) {
            const int n = g * 128 + wave * 32 + j * 16 + l15;
#pragma unroll
            for (int kt = 0; kt < 4; ++kt)
                wf[g * 8 + j * 4 + kt] = load_w8(Whh1 + n * H1 + kt * 32 + quad * 8);
            wf[32 + g * 2 + j] = load_w8(Wih1 + n * F_IN + quad * 8);
            bias[g * 2 + j] = bih1[n] + bhh1[n];
        }

    // zero LDS (A-operand reads rows 0..15; rows >= ROWS stay zero)
    for (int i = tid; i < 2 * 16 * 72;  i += 256) ((ushort*)xs)[i]  = 0;
    for (int i = tid; i < 2 * 16 * 264; i += 256) ((ushort*)h1b)[i] = 0;
    for (int i = tid; i < 2 * 16 * 136; i += 256) ((ushort*)h2b)[i] = 0;

    // prime xs[0] = x(0): tid<64 -> (row = tid>>5, col = tid&31)
    const int xrow = tid >> 5, xcol = tid & 31;
    const float* xptr = x + ((size_t)(r0 + (xrow & 1)) * T_SEQ) * F_IN + xcol;
    if (tid < 64) {
        const float v = xptr[0];
        const ushort h = f2bf(v);
        xs[0][xrow][xcol]      = h;
        xs[0][xrow][32 + xcol] = f2bf(v - bf2f(h));
    }
    __syncthreads();

    // ---------------- PHASE 1: layer 1 ----------------
    {
        float cst[4];   // c1 for (j<2, r<2) on quad-0 lanes
#pragma unroll
        for (int i = 0; i < 4; ++i) cst[i] = 0.0f;

        float xreg = (tid < 64 && T_SEQ > 1) ? xptr[1 * F_IN] : 0.0f;

        f32x4 acc[8];

#pragma unroll 1
        for (int t = 0; t < T_SEQ; ++t) {
            const int pr = t & 1, pw = pr ^ 1;

            // stage x(t+1) -> xs[pw]; prefetch x(t+2)
            if (tid < 64 && t + 1 < T_SEQ) {
                const ushort h = f2bf(xreg);
                xs[pw][xrow][xcol]      = h;
                xs[pw][xrow][32 + xcol] = f2bf(xreg - bf2f(h));
                if (t + 2 < T_SEQ) xreg = xptr[(t + 2) * F_IN];
            }

            // gates for all 4 types of this wave's 32 units
#pragma unroll
            for (int i = 0; i < 8; ++i)
                acc[i] = (f32x4){bias[i], bias[i], bias[i], bias[i]};
#pragma unroll
            for (int xt = 0; xt < 2; ++xt) {   // x hi, lo
                const bf16x8 ax = *(const bf16x8*)&xs[pr][l15][xt * 32 + quad * 8];
#pragma unroll
                for (int i = 0; i < 8; ++i)
                    acc[i] = MFMA16(ax, wf[32 + i], acc[i]);
            }
#pragma unroll
            for (int kt = 0; kt < 8; ++kt) {   // h1 hi (0-3), lo (4-7)
                const bf16x8 ah = *(const bf16x8*)&h1b[pr][l15][kt * 32 + quad * 8];
#pragma unroll
                for (int g = 0; g < 4; ++g)
#pragma unroll
                    for (int j = 0; j < 2; ++j)
                        acc[g * 2 + j] =
                            MFMA16(ah, wf[g * 8 + j * 4 + (kt & 3)], acc[g * 2 + j]);
            }

            // in-register epilogue: quad-0 lanes hold C rows 0..1
            if (quad == 0) {
#pragma unroll
                for (int j = 0; j < 2; ++j) {
                    const int u = wave * 32 + j * 16 + l15;
#pragma unroll
                    for (int r = 0; r < ROWS; ++r) {
                        const float iv = fast_sigmoid(acc[0 * 2 + j][r]);
                        const float fv = fast_sigmoid(acc[1 * 2 + j][r]);
                        const float gv = fast_tanh   (acc[2 * 2 + j][r]);
                        const float ov = fast_sigmoid(acc[3 * 2 + j][r]);
                        const float cn = fv * cst[j * 2 + r] + iv * gv;
                        cst[j * 2 + r] = cn;
                        const float h = ov * fast_tanh(cn);
                        const ushort hi = f2bf(h);
                        h1b[pw][r][u]       = hi;
                        h1b[pw][r][128 + u] = f2bf(h - bf2f(hi));
                        h1ws[((size_t)(r0 + r) * T_SEQ + t) * H1 + u] = hi;
                    }
                }
            }
            bar_lds();   // single barrier: step-t ds writes -> step-(t+1) reads
        }
    }

    __syncthreads();   // full drain: h1ws global writes visible for phase 2

    // ---- phase-2 weights: wave owns units w*16 + l15, all gates.
    //  wf[g*4 + kt] = Wih2 (K=128, hi only); wf[16 + g*2 + kt] = Whh2 (kt<2)
#pragma unroll
    for (int g = 0; g < 4; ++g) {
        const int n = g * 64 + wave * 16 + l15;
#pragma unroll
        for (int kt = 0; kt < 4; ++kt)
            wf[g * 4 + kt] = load_w8(Wih2 + n * H1 + kt * 32 + quad * 8);
#pragma unroll
        for (int kt = 0; kt < 2; ++kt)
            wf[16 + g * 2 + kt] = load_w8(Whh2 + n * E2 + kt * 32 + quad * 8);
        bias[g] = bih2[n] + bhh2[n];
    }

    // prime h1 staging: h1b[0] rows 0..1, cols 0..127 <- h1(0) from d_ws
    const int srow = tid >> 6, su = tid & 63;    // tid < 128
    const uint* uptr = (const uint*)h1ws + ((size_t)(r0 + (srow & 1)) * T_SEQ) * 64 + su;
    if (tid < 128) *(uint*)&h1b[0][srow][2 * su] = uptr[0];
    uint ureg = (tid < 128 && T_SEQ > 1) ? uptr[(size_t)1 * 64] : 0u;
    __syncthreads();

    // ---------------- PHASE 2: layer 2 ----------------
    {
        float cst[2];   // c2 for r<2 on quad-0 lanes
        cst[0] = cst[1] = 0.0f;

        f32x4 acc[4];

#pragma unroll 1
        for (int t = 0; t < T_SEQ; ++t) {
            const int pr = t & 1, pw = pr ^ 1;

            // stage h1(t+1) -> h1b[pw]; prefetch h1(t+2)
            if (tid < 128 && t + 1 < T_SEQ) {
                *(uint*)&h1b[pw][srow][2 * su] = ureg;
                if (t + 2 < T_SEQ) ureg = uptr[(size_t)(t + 2) * 64];
            }

#pragma unroll
            for (int g = 0; g < 4; ++g)
                acc[g] = (f32x4){bias[g], bias[g], bias[g], bias[g]};
#pragma unroll
            for (int kt = 0; kt < 4; ++kt) {   // h1 hi (cols 0..127)
                const bf16x8 a = *(const bf16x8*)&h1b[pr][l15][kt * 32 + quad * 8];
#pragma unroll
                for (int g = 0; g < 4; ++g)
                    acc[g] = MFMA16(a, wf[g * 4 + kt], acc[g]);
            }
#pragma unroll
            for (int kt = 0; kt < 4; ++kt) {   // h2 hi (0-1), lo (2-3)
                const bf16x8 a = *(const bf16x8*)&h2b[pr][l15][kt * 32 + quad * 8];
#pragma unroll
                for (int g = 0; g < 4; ++g)
                    acc[g] = MFMA16(a, wf[16 + g * 2 + (kt & 1)], acc[g]);
            }

            if (quad == 0) {
                const int u = wave * 16 + l15;
#pragma unroll
                for (int r = 0; r < ROWS; ++r) {
                    const float iv = fast_sigmoid(acc[0][r]);
                    const float fv = fast_sigmoid(acc[1][r]);
                    const float gv = fast_tanh   (acc[2][r]);
                    const float ov = fast_sigmoid(acc[3][r]);
                    const float cn = fv * cst[r] + iv * gv;
                    cst[r] = cn;
                    const float h = ov * fast_tanh(cn);
                    const ushort hi = f2bf(h);
                    h2b[pw][r][u]      = hi;
                    h2b[pw][r][64 + u] = f2bf(h - bf2f(hi));
                    if (t == T_SEQ - 1)
                        out[(size_t)(r0 + r) * E2 + u] = h;
                }
            }
            bar_lds();
        }
    }
}

extern "C" void kernel_launch(void* const* d_in, const int* in_sizes, int n_in,
                              void* d_out, int out_size, void* d_ws, size_t ws_size,
                              hipStream_t stream) {
    lstm_fused<<<256, 256, 0, stream>>>(
        (const float*)d_in[0], (const float*)d_in[1], (const float*)d_in[2],
        (const float*)d_in[3], (const float*)d_in[4], (const float*)d_in[5],
        (const float*)d_in[6], (const float*)d_in[7], (const float*)d_in[8],
        (ushort*)d_ws, (float*)d_out);
}